// Round 4
// baseline (152.924 us; speedup 1.0000x reference)
//
#include <hip/hip_runtime.h>
#include <hip/hip_bf16.h>

typedef __bf16 bf16_t;
typedef __bf16 bf16x8 __attribute__((ext_vector_type(8)));
typedef __bf16 bf16x4 __attribute__((ext_vector_type(4)));
typedef short  s16x4  __attribute__((ext_vector_type(4)));
typedef float  f32x4  __attribute__((ext_vector_type(4)));

#define B_DIM 8
#define C_DIM 512
#define T_DIM 1024
#define NH 8
#define HD 64

// softmax scale^2 * log2(e), folded into Q at the qkv epilogue
#define QSCALE 0.180336880111112f

// v_mfma_f32_16x16x16_bf16 (gfx950 ISA §10): A/B = 4 bf16 (2 VGPRs),
// operand layout k=quad*4+j, m/n=l15; C row=quad*4+r, col=l15.
__device__ __forceinline__ f32x4 mfma16_bf16(bf16x4 a, bf16x4 b, f32x4 c) {
    return __builtin_amdgcn_mfma_f32_16x16x16bf16_1k(
        __builtin_bit_cast(s16x4, a), __builtin_bit_cast(s16x4, b), c, 0, 0, 0);
}

// raw barrier: make LDS writes visible, but do NOT drain vmcnt (prefetch
// loads stay in flight across the barrier — T4 style).
__device__ __forceinline__ void block_sync_lds() {
    asm volatile("s_waitcnt lgkmcnt(0)" ::: "memory");
    __builtin_amdgcn_s_barrier();
}

// ---------------------------------------------------------------------------
// Kernel 0: one-time weight conversion fp32 -> bf16.
// ---------------------------------------------------------------------------
__global__ __launch_bounds__(256) void prep_w(const float* __restrict__ w1,
                                              const float* __restrict__ w2,
                                              bf16_t* __restrict__ o1,
                                              bf16_t* __restrict__ o2)
{
    int tid = blockIdx.x * 256 + threadIdx.x;
    for (int p = 0; p < 4; ++p) {
        int q = tid + p * 65536;
        const f32x4* src;
        bf16x4* dst;
        int qq;
        if (q < 196608) { src = (const f32x4*)w1; dst = (bf16x4*)o1; qq = q; }
        else            { src = (const f32x4*)w2; dst = (bf16x4*)o2; qq = q - 196608; }
        f32x4 f = src[qq];
        bf16x4 h;
        for (int j = 0; j < 4; ++j) h[j] = (bf16_t)f[j];
        dst[qq] = h;
    }
}

// ---------------------------------------------------------------------------
// Kernel 1: GroupNorm.  x (b,c,t) fp32 -> n_t (b,t,c) bf16.  (unchanged)
// ---------------------------------------------------------------------------
__global__ __launch_bounds__(256) void gn_kernel(const float* __restrict__ x,
                                                 const float* __restrict__ gw,
                                                 const float* __restrict__ gb,
                                                 bf16_t* __restrict__ n_t)
{
    __shared__ bf16_t sX[16384];
    __shared__ float sred[8];
    int tid = threadIdx.x;
    int bb  = blockIdx.x >> 5;
    int g   = blockIdx.x & 31;
    const f32x4* xg4 = reinterpret_cast<const f32x4*>(x + (size_t)(bb * C_DIM + g * 16) * T_DIM);

    float s = 0.f, sq = 0.f;
    for (int i = 0; i < 16; ++i) {
        int v = tid + i * 256;
        f32x4 f = xg4[v];
        bf16x4 h;
        for (int j = 0; j < 4; ++j) {
            s += f[j]; sq += f[j] * f[j];
            h[j] = (bf16_t)f[j];
        }
        *reinterpret_cast<bf16x4*>(sX + v * 4) = h;
    }
    for (int off = 1; off < 64; off <<= 1) {
        s  += __shfl_xor(s, off);
        sq += __shfl_xor(sq, off);
    }
    int wv = tid >> 6;
    if ((tid & 63) == 0) { sred[wv * 2] = s; sred[wv * 2 + 1] = sq; }
    __syncthreads();
    s  = sred[0] + sred[2] + sred[4] + sred[6];
    sq = sred[1] + sred[3] + sred[5] + sred[7];
    float mean = s * (1.f / 16384.f);
    float var  = sq * (1.f / 16384.f) - mean * mean;
    float rs   = rsqrtf(var + 1e-5f);

    int hf = tid & 1;
    float aa[8], bbias[8];
    for (int j = 0; j < 8; ++j) {
        int c = hf * 8 + j;
        float av = gw[g * 16 + c] * rs;
        aa[j] = av;
        bbias[j] = gb[g * 16 + c] - mean * av;
    }
    bf16_t* ob = n_t + (size_t)bb * T_DIM * C_DIM + g * 16 + hf * 8;
    for (int p = 0; p < 8; ++p) {
        int t = (tid >> 1) + p * 128;
        bf16x8 o;
        for (int j = 0; j < 8; ++j) {
            float xv = (float)sX[(hf * 8 + j) * 1024 + t];
            o[j] = (bf16_t)(xv * aa[j] + bbias[j]);
        }
        *reinterpret_cast<bf16x8*>(ob + (size_t)t * C_DIM) = o;
    }
}

// ---------------------------------------------------------------------------
// Kernel 2: QKV GEMM, round 13: 128x128 tile, 4 waves, 64x64 per wave
// (acc[4][4]).  MFMA : ds_read_b128 ratio 2.0.  Epilogue handles two 64-row
// output chunks (chunk = 2*bx + half); store loops are 4 iterations each
// (128 t x 64 c = 1024 bf16x8 per chunk — R3's i<2 was the correctness bug).
// ---------------------------------------------------------------------------
__global__ __launch_bounds__(256, 4) void qkv_gemm_kernel(
    const bf16_t* __restrict__ wqb, const float* __restrict__ bq,
    const bf16_t* __restrict__ n_t, bf16_t* __restrict__ qkv)
{
    __shared__ bf16_t sA[128 * 72];
    __shared__ bf16_t sB[128 * 72];
    int tid = threadIdx.x;
    int w = tid >> 6, lane = tid & 63, quad = lane >> 4, l15 = lane & 15;
    int bx = blockIdx.x;          // 0..11  (two 64-row chunks each)
    int t0 = blockIdx.y * 128;
    int bb = blockIdx.z;
    int o0 = bx * 128;
    const bf16_t* Ab = wqb + (size_t)o0 * C_DIM;
    const bf16_t* Bb = n_t + ((size_t)bb * T_DIM + t0) * C_DIM;

    f32x4 acc[4][4];
    for (int mt = 0; mt < 4; ++mt)
        for (int nt = 0; nt < 4; ++nt)
            acc[mt][nt] = f32x4{0.f, 0.f, 0.f, 0.f};
    int mw0 = (w >> 1) * 64;      // 0 or 64
    int nw0 = (w & 1) * 64;       // 0 or 64

    for (int k0 = 0; k0 < C_DIM; k0 += 64) {
        for (int i = 0; i < 4; ++i) {
            int v = tid + i * 256;
            int row = v >> 3, c8 = v & 7;
            *reinterpret_cast<bf16x8*>(sA + row * 72 + c8 * 8) =
                *reinterpret_cast<const bf16x8*>(Ab + (size_t)row * C_DIM + k0 + c8 * 8);
        }
        for (int i = 0; i < 4; ++i) {
            int v = tid + i * 256;
            int row = v >> 3, c8 = v & 7;
            *reinterpret_cast<bf16x8*>(sB + row * 72 + c8 * 8) =
                *reinterpret_cast<const bf16x8*>(Bb + (size_t)row * C_DIM + k0 + c8 * 8);
        }
        __syncthreads();
        for (int kk = 0; kk < 2; ++kk) {
            bf16x8 af[4], bfr[4];
            for (int mt = 0; mt < 4; ++mt)
                af[mt] = *reinterpret_cast<const bf16x8*>(sA + (mw0 + mt * 16 + l15) * 72 + kk * 32 + quad * 8);
            for (int nt = 0; nt < 4; ++nt)
                bfr[nt] = *reinterpret_cast<const bf16x8*>(sB + (nw0 + nt * 16 + l15) * 72 + kk * 32 + quad * 8);
            for (int mt = 0; mt < 4; ++mt)
                for (int nt = 0; nt < 4; ++nt)
                    acc[mt][nt] = __builtin_amdgcn_mfma_f32_16x16x32_bf16(af[mt], bfr[nt], acc[mt][nt], 0, 0, 0);
        }
        __syncthreads();
    }

    // epilogue: two 64-row output chunks; wave-half (w>>1) owns chunk half.
    for (int half = 0; half < 2; ++half) {
        int chunk = bx * 2 + half;
        int h = chunk / 3, type = chunk % 3;
        size_t base = ((size_t)(bb * NH + h) * 3 + type) * (64 * 1024);
        bool mine = (mw0 >> 6) == half;

        if (type < 2) {
            float scl = (type == 0) ? QSCALE : 1.0f;
            if (mine)
                for (int mt = 0; mt < 4; ++mt)
                    for (int nt = 0; nt < 4; ++nt)
                        for (int r = 0; r < 4; ++r) {
                            int mw = mt * 16 + quad * 4 + r;          // 0..63 within chunk
                            int tl = nw0 + nt * 16 + l15;             // 0..127
                            float v = (acc[mt][nt][r] + bq[o0 + half * 64 + mw]) * scl;
                            sB[tl * 72 + mw] = (bf16_t)v;
                        }
            __syncthreads();
            for (int i = 0; i < 4; ++i) {
                int v = tid + i * 256;
                int tl = v >> 3, c8 = v & 7;
                bf16x8 d = *reinterpret_cast<const bf16x8*>(sB + tl * 72 + c8 * 8);
                *reinterpret_cast<bf16x8*>(qkv + base + (size_t)(t0 + tl) * 64 + c8 * 8) = d;
            }
            __syncthreads();
        } else {
            if (mine)
                for (int mt = 0; mt < 4; ++mt)
                    for (int nt = 0; nt < 4; ++nt)
                        for (int r = 0; r < 4; ++r) {
                            int mw = mt * 16 + quad * 4 + r;
                            int tl = nw0 + nt * 16 + l15;
                            float v = acc[mt][nt][r] + bq[o0 + half * 64 + mw];
                            sB[mw * 136 + tl] = (bf16_t)v;
                        }
            __syncthreads();
            for (int i = 0; i < 4; ++i) {
                int v = tid + i * 256;
                int cc = v >> 4, t8 = (v & 15) * 8;
                bf16x8 d = *reinterpret_cast<const bf16x8*>(sB + cc * 136 + t8);
                *reinterpret_cast<bf16x8*>(qkv + base + (size_t)cc * 1024 + t0 + t8) = d;
            }
            __syncthreads();
        }
    }
}

// ---------------------------------------------------------------------------
// Kernel 3: flash attention (unchanged from round 11).
// ---------------------------------------------------------------------------
__global__ __launch_bounds__(256, 2) void attn_kernel(const bf16_t* __restrict__ qkv,
                                                      bf16_t* __restrict__ net_t)
{
    __shared__ bf16_t sK0[64 * 72];
    __shared__ bf16_t sV0[64 * 72];
    __shared__ bf16_t sK1[64 * 72];
    __shared__ bf16_t sV1[64 * 72];
    int tid = threadIdx.x;
    int w = tid >> 6, lane = tid & 63, quad = lane >> 4, l15 = lane & 15;
    int bh = blockIdx.x;
    int qt = blockIdx.y;                 // 0..7, 128 t-rows per block
    size_t qb = (size_t)bh * 3 * 65536;
    const bf16_t* Qg = qkv + qb + (size_t)qt * 8192;   // 128 rows x 64
    const bf16_t* Kg = qkv + qb + 65536;
    const bf16_t* Vg = qkv + qb + 2 * 65536;

    bf16x8 qf[2][2];
    for (int tt = 0; tt < 2; ++tt)
        for (int kk = 0; kk < 2; ++kk)
            qf[tt][kk] = *reinterpret_cast<const bf16x8*>(
                Qg + (size_t)(tt * 64 + w * 16 + l15) * 64 + kk * 32 + quad * 8);

    int vrow = tid >> 3;            // 0..31
    int vcol = (tid & 7) * 8;       // 0..56

    bf16x8 kA[2], vA[2], kB[2], vB[2];

    auto load_tiles = [&](bf16x8* kr, bf16x8* vr, int s0) {
        for (int i = 0; i < 2; ++i) {
            int r = vrow + i * 32;
            kr[i] = *reinterpret_cast<const bf16x8*>(Kg + (size_t)(s0 + r) * 64 + vcol);
            vr[i] = *reinterpret_cast<const bf16x8*>(Vg + (size_t)r * 1024 + s0 + vcol);
        }
    };
    auto write_tiles = [&](bf16_t* sKb, bf16_t* sVb, const bf16x8* kr, const bf16x8* vr) {
        for (int i = 0; i < 2; ++i) {
            int r = vrow + i * 32;
            *reinterpret_cast<bf16x8*>(sKb + r * 72 + vcol) = kr[i];
            *reinterpret_cast<bf16x8*>(sVb + r * 72 + vcol) = vr[i];
        }
    };

    f32x4 O0[4], O1[4];
    for (int i = 0; i < 4; ++i) {
        O0[i] = f32x4{0.f, 0.f, 0.f, 0.f};
        O1[i] = f32x4{0.f, 0.f, 0.f, 0.f};
    }
    f32x4 L0 = f32x4{0.f, 0.f, 0.f, 0.f};
    f32x4 L1 = f32x4{0.f, 0.f, 0.f, 0.f};
    const bf16x4 kONES = bf16x4{(bf16_t)1.f, (bf16_t)1.f, (bf16_t)1.f, (bf16_t)1.f};

    auto compute_tile = [&](const bf16_t* sKb, const bf16_t* sVb) {
        __builtin_amdgcn_s_setprio(1);
        for (int mt = 0; mt < 4; ++mt) {
            const bf16_t* krow = sKb + (mt * 16 + l15) * 72 + quad * 8;
            bf16x8 kf0 = *reinterpret_cast<const bf16x8*>(krow);
            bf16x8 kf1 = *reinterpret_cast<const bf16x8*>(krow + 32);
            f32x4 S0 = f32x4{0.f, 0.f, 0.f, 0.f};
            f32x4 S1 = f32x4{0.f, 0.f, 0.f, 0.f};
            S0 = __builtin_amdgcn_mfma_f32_16x16x32_bf16(kf0, qf[0][0], S0, 0, 0, 0);
            S1 = __builtin_amdgcn_mfma_f32_16x16x32_bf16(kf0, qf[1][0], S1, 0, 0, 0);
            S0 = __builtin_amdgcn_mfma_f32_16x16x32_bf16(kf1, qf[0][1], S0, 0, 0, 0);
            S1 = __builtin_amdgcn_mfma_f32_16x16x32_bf16(kf1, qf[1][1], S1, 0, 0, 0);
            bf16x4 pf0, pf1;
            for (int r = 0; r < 4; ++r) {
                pf0[r] = (bf16_t)__builtin_amdgcn_exp2f(S0[r]);
                pf1[r] = (bf16_t)__builtin_amdgcn_exp2f(S1[r]);
            }
            L0 = mfma16_bf16(kONES, pf0, L0);
            L1 = mfma16_bf16(kONES, pf1, L1);
            for (int ct = 0; ct < 4; ++ct) {
                bf16x4 vf = *reinterpret_cast<const bf16x4*>(sVb + (ct * 16 + l15) * 72 + mt * 16 + quad * 4);
                O0[ct] = mfma16_bf16(vf, pf0, O0[ct]);
                O1[ct] = mfma16_bf16(vf, pf1, O1[ct]);
            }
        }
        __builtin_amdgcn_s_setprio(0);
    };

    load_tiles(kA, vA, 0);
    write_tiles(sK0, sV0, kA, vA);
    load_tiles(kB, vB, 64);
    block_sync_lds();

    for (int st2 = 0; st2 < 8; ++st2) {
        write_tiles(sK1, sV1, kB, vB);
        if (st2 < 7) load_tiles(kA, vA, (2 * st2 + 2) * 64);
        compute_tile(sK0, sV0);
        block_sync_lds();
        if (st2 < 7) {
            write_tiles(sK0, sV0, kA, vA);
            load_tiles(kB, vB, (2 * st2 + 3) * 64);
        }
        compute_tile(sK1, sV1);
        if (st2 < 7) block_sync_lds();
    }

    float inv0 = 1.f / L0[0];
    float inv1 = 1.f / L1[0];

    int bb = bh >> 3, h = bh & 7;
    int tbase = qt * 128 + w * 16 + l15;
    bf16_t* orow0 = net_t + ((size_t)bb * T_DIM + tbase) * C_DIM + h * 64;
    bf16_t* orow1 = net_t + ((size_t)bb * T_DIM + tbase + 64) * C_DIM + h * 64;
    for (int ct = 0; ct < 4; ++ct) {
        bf16x4 o4, o5;
        for (int r = 0; r < 4; ++r) {
            o4[r] = (bf16_t)(O0[ct][r] * inv0);
            o5[r] = (bf16_t)(O1[ct][r] * inv1);
        }
        *reinterpret_cast<bf16x4*>(orow0 + ct * 16 + quad * 4) = o4;
        *reinterpret_cast<bf16x4*>(orow1 + ct * 16 + quad * 4) = o5;
    }
}

// ---------------------------------------------------------------------------
// Kernel 4: out GEMM + bias + residual (unchanged).
// ---------------------------------------------------------------------------
__global__ __launch_bounds__(256) void out_gemm_kernel(
    const bf16_t* __restrict__ wob, const float* __restrict__ bo,
    const bf16_t* __restrict__ net_t, const float* __restrict__ x,
    float* __restrict__ out)
{
    __shared__ bf16_t sA[64 * 72];
    __shared__ bf16_t sB[128 * 72];
    int tid = threadIdx.x;
    int w = tid >> 6, lane = tid & 63, quad = lane >> 4, l15 = lane & 15;
    int o0 = blockIdx.x * 64;
    int t0 = blockIdx.y * 128;
    int bb = blockIdx.z;
    const bf16_t* Ab = wob + (size_t)o0 * C_DIM;
    const bf16_t* Bb = net_t + ((size_t)bb * T_DIM + t0) * C_DIM;

    f32x4 acc[2][4];
    for (int mt = 0; mt < 2; ++mt)
        for (int nt = 0; nt < 4; ++nt)
            acc[mt][nt] = f32x4{0.f, 0.f, 0.f, 0.f};
    int mw0 = (w >> 1) * 32;
    int nw0 = (w & 1) * 64;

    for (int k0 = 0; k0 < C_DIM; k0 += 64) {
        for (int i = 0; i < 2; ++i) {
            int v = tid + i * 256;
            int row = v >> 3, c8 = v & 7;
            *reinterpret_cast<bf16x8*>(sA + row * 72 + c8 * 8) =
                *reinterpret_cast<const bf16x8*>(Ab + (size_t)row * C_DIM + k0 + c8 * 8);
        }
        for (int i = 0; i < 4; ++i) {
            int v = tid + i * 256;
            int row = v >> 3, c8 = v & 7;
            *reinterpret_cast<bf16x8*>(sB + row * 72 + c8 * 8) =
                *reinterpret_cast<const bf16x8*>(Bb + (size_t)row * C_DIM + k0 + c8 * 8);
        }
        __syncthreads();
        for (int kk = 0; kk < 2; ++kk) {
            bf16x8 af[2], bfr[4];
            for (int mt = 0; mt < 2; ++mt)
                af[mt] = *reinterpret_cast<const bf16x8*>(sA + (mw0 + mt * 16 + l15) * 72 + kk * 32 + quad * 8);
            for (int nt = 0; nt < 4; ++nt)
                bfr[nt] = *reinterpret_cast<const bf16x8*>(sB + (nw0 + nt * 16 + l15) * 72 + kk * 32 + quad * 8);
            for (int mt = 0; mt < 2; ++mt)
                for (int nt = 0; nt < 4; ++nt)
                    acc[mt][nt] = __builtin_amdgcn_mfma_f32_16x16x32_bf16(af[mt], bfr[nt], acc[mt][nt], 0, 0, 0);
        }
        __syncthreads();
    }

    for (int mt = 0; mt < 2; ++mt)
        for (int nt = 0; nt < 4; ++nt)
            for (int r = 0; r < 4; ++r) {
                int o = o0 + mw0 + mt * 16 + quad * 4 + r;
                int t = t0 + nw0 + nt * 16 + l15;
                size_t idx = ((size_t)bb * C_DIM + o) * T_DIM + t;
                out[idx] = acc[mt][nt][r] + bo[o] + x[idx];
            }
}

// ---------------------------------------------------------------------------
extern "C" void kernel_launch(void* const* d_in, const int* in_sizes, int n_in,
                              void* d_out, int out_size, void* d_ws, size_t ws_size,
                              hipStream_t stream)
{
    const float* x     = (const float*)d_in[0];
    const float* gn_w  = (const float*)d_in[1];
    const float* gn_b  = (const float*)d_in[2];
    const float* qkv_w = (const float*)d_in[3];
    const float* qkv_b = (const float*)d_in[4];
    const float* out_w = (const float*)d_in[5];
    const float* out_b = (const float*)d_in[6];
    float* out = (float*)d_out;

    // ws layout (bf16): n_t 8MB | qkv 24MB | net_t 8MB | wqb 1.5MB | wob 0.5MB
    char* ws = (char*)d_ws;
    bf16_t* n_t   = (bf16_t*)(ws);
    bf16_t* qkv   = (bf16_t*)(ws + 8388608);
    bf16_t* net_t = (bf16_t*)(ws + 33554432);
    bf16_t* wqb   = (bf16_t*)(ws + 41943040);
    bf16_t* wob   = (bf16_t*)(ws + 41943040 + 1572864);

    prep_w<<<dim3(256), 256, 0, stream>>>(qkv_w, out_w, wqb, wob);
    gn_kernel<<<dim3(256), 256, 0, stream>>>(x, gn_w, gn_b, n_t);
    qkv_gemm_kernel<<<dim3(12, 8, 8), 256, 0, stream>>>(wqb, qkv_b, n_t, qkv);
    attn_kernel<<<dim3(64, 8), 256, 0, stream>>>(qkv, net_t);
    out_gemm_kernel<<<dim3(8, 8, 8), 256, 0, stream>>>(wob, out_b, net_t, x, out);
}

// Round 5
// 149.692 us; speedup vs baseline: 1.0216x; 1.0216x over previous
//
#include <hip/hip_runtime.h>
#include <hip/hip_bf16.h>

typedef __bf16 bf16_t;
typedef __bf16 bf16x8 __attribute__((ext_vector_type(8)));
typedef __bf16 bf16x4 __attribute__((ext_vector_type(4)));
typedef short  s16x4  __attribute__((ext_vector_type(4)));
typedef float  f32x4  __attribute__((ext_vector_type(4)));

#define B_DIM 8
#define C_DIM 512
#define T_DIM 1024
#define NH 8
#define HD 64

// softmax scale^2 * log2(e), folded into Q at the qkv epilogue
#define QSCALE 0.180336880111112f

// v_mfma_f32_16x16x16_bf16 (gfx950 ISA §10): A/B = 4 bf16 (2 VGPRs),
// operand layout k=quad*4+j, m/n=l15; C row=quad*4+r, col=l15.
__device__ __forceinline__ f32x4 mfma16_bf16(bf16x4 a, bf16x4 b, f32x4 c) {
    return __builtin_amdgcn_mfma_f32_16x16x16bf16_1k(
        __builtin_bit_cast(s16x4, a), __builtin_bit_cast(s16x4, b), c, 0, 0, 0);
}

// raw barrier: make LDS writes visible, but do NOT drain vmcnt (prefetch
// loads stay in flight across the barrier — T4 style).
__device__ __forceinline__ void block_sync_lds() {
    asm volatile("s_waitcnt lgkmcnt(0)" ::: "memory");
    __builtin_amdgcn_s_barrier();
}

// ---------------------------------------------------------------------------
// Kernel 1: GroupNorm + fused one-time weight conversion.
//   blocks   0..255 : GroupNorm  x (b,c,t) fp32 -> n_t (b,t,c) bf16
//   blocks 256..319 : fp32 -> bf16 conversion of qkv_w / out_w
// ---------------------------------------------------------------------------
__global__ __launch_bounds__(256) void gn_kernel(const float* __restrict__ x,
                                                 const float* __restrict__ gw,
                                                 const float* __restrict__ gb,
                                                 bf16_t* __restrict__ n_t,
                                                 const float* __restrict__ w1,
                                                 const float* __restrict__ w2,
                                                 bf16_t* __restrict__ o1,
                                                 bf16_t* __restrict__ o2)
{
    __shared__ bf16_t sX[16384];
    __shared__ float sred[8];
    int tid = threadIdx.x;

    if (blockIdx.x >= 256) {
        // ---- weight conversion: 64 blocks x 256 threads x 16 = 262144 f32x4
        int tid2 = (blockIdx.x - 256) * 256 + tid;
        for (int p = 0; p < 16; ++p) {
            int q = tid2 + p * 16384;
            const f32x4* src;
            bf16x4* dst;
            int qq;
            if (q < 196608) { src = (const f32x4*)w1; dst = (bf16x4*)o1; qq = q; }
            else            { src = (const f32x4*)w2; dst = (bf16x4*)o2; qq = q - 196608; }
            f32x4 f = src[qq];
            bf16x4 h;
            for (int j = 0; j < 4; ++j) h[j] = (bf16_t)f[j];
            dst[qq] = h;
        }
        return;
    }

    int bb  = blockIdx.x >> 5;
    int g   = blockIdx.x & 31;
    const f32x4* xg4 = reinterpret_cast<const f32x4*>(x + (size_t)(bb * C_DIM + g * 16) * T_DIM);

    float s = 0.f, sq = 0.f;
    for (int i = 0; i < 16; ++i) {
        int v = tid + i * 256;
        f32x4 f = xg4[v];
        bf16x4 h;
        for (int j = 0; j < 4; ++j) {
            s += f[j]; sq += f[j] * f[j];
            h[j] = (bf16_t)f[j];
        }
        *reinterpret_cast<bf16x4*>(sX + v * 4) = h;
    }
    for (int off = 1; off < 64; off <<= 1) {
        s  += __shfl_xor(s, off);
        sq += __shfl_xor(sq, off);
    }
    int wv = tid >> 6;
    if ((tid & 63) == 0) { sred[wv * 2] = s; sred[wv * 2 + 1] = sq; }
    __syncthreads();
    s  = sred[0] + sred[2] + sred[4] + sred[6];
    sq = sred[1] + sred[3] + sred[5] + sred[7];
    float mean = s * (1.f / 16384.f);
    float var  = sq * (1.f / 16384.f) - mean * mean;
    float rs   = rsqrtf(var + 1e-5f);

    int hf = tid & 1;
    float aa[8], bbias[8];
    for (int j = 0; j < 8; ++j) {
        int c = hf * 8 + j;
        float av = gw[g * 16 + c] * rs;
        aa[j] = av;
        bbias[j] = gb[g * 16 + c] - mean * av;
    }
    bf16_t* ob = n_t + (size_t)bb * T_DIM * C_DIM + g * 16 + hf * 8;
    for (int p = 0; p < 8; ++p) {
        int t = (tid >> 1) + p * 128;
        bf16x8 o;
        for (int j = 0; j < 8; ++j) {
            float xv = (float)sX[(hf * 8 + j) * 1024 + t];
            o[j] = (bf16_t)(xv * aa[j] + bbias[j]);
        }
        *reinterpret_cast<bf16x8*>(ob + (size_t)t * C_DIM) = o;
    }
}

// ---------------------------------------------------------------------------
// Kernel 2: QKV GEMM (128x128 tile, verified R4 version, unchanged).
// ---------------------------------------------------------------------------
__global__ __launch_bounds__(256, 4) void qkv_gemm_kernel(
    const bf16_t* __restrict__ wqb, const float* __restrict__ bq,
    const bf16_t* __restrict__ n_t, bf16_t* __restrict__ qkv)
{
    __shared__ bf16_t sA[128 * 72];
    __shared__ bf16_t sB[128 * 72];
    int tid = threadIdx.x;
    int w = tid >> 6, lane = tid & 63, quad = lane >> 4, l15 = lane & 15;
    int bx = blockIdx.x;          // 0..11  (two 64-row chunks each)
    int t0 = blockIdx.y * 128;
    int bb = blockIdx.z;
    int o0 = bx * 128;
    const bf16_t* Ab = wqb + (size_t)o0 * C_DIM;
    const bf16_t* Bb = n_t + ((size_t)bb * T_DIM + t0) * C_DIM;

    f32x4 acc[4][4];
    for (int mt = 0; mt < 4; ++mt)
        for (int nt = 0; nt < 4; ++nt)
            acc[mt][nt] = f32x4{0.f, 0.f, 0.f, 0.f};
    int mw0 = (w >> 1) * 64;      // 0 or 64
    int nw0 = (w & 1) * 64;       // 0 or 64

    for (int k0 = 0; k0 < C_DIM; k0 += 64) {
        for (int i = 0; i < 4; ++i) {
            int v = tid + i * 256;
            int row = v >> 3, c8 = v & 7;
            *reinterpret_cast<bf16x8*>(sA + row * 72 + c8 * 8) =
                *reinterpret_cast<const bf16x8*>(Ab + (size_t)row * C_DIM + k0 + c8 * 8);
        }
        for (int i = 0; i < 4; ++i) {
            int v = tid + i * 256;
            int row = v >> 3, c8 = v & 7;
            *reinterpret_cast<bf16x8*>(sB + row * 72 + c8 * 8) =
                *reinterpret_cast<const bf16x8*>(Bb + (size_t)row * C_DIM + k0 + c8 * 8);
        }
        __syncthreads();
        for (int kk = 0; kk < 2; ++kk) {
            bf16x8 af[4], bfr[4];
            for (int mt = 0; mt < 4; ++mt)
                af[mt] = *reinterpret_cast<const bf16x8*>(sA + (mw0 + mt * 16 + l15) * 72 + kk * 32 + quad * 8);
            for (int nt = 0; nt < 4; ++nt)
                bfr[nt] = *reinterpret_cast<const bf16x8*>(sB + (nw0 + nt * 16 + l15) * 72 + kk * 32 + quad * 8);
            for (int mt = 0; mt < 4; ++mt)
                for (int nt = 0; nt < 4; ++nt)
                    acc[mt][nt] = __builtin_amdgcn_mfma_f32_16x16x32_bf16(af[mt], bfr[nt], acc[mt][nt], 0, 0, 0);
        }
        __syncthreads();
    }

    // epilogue: two 64-row output chunks; wave-half (w>>1) owns chunk half.
    for (int half = 0; half < 2; ++half) {
        int chunk = bx * 2 + half;
        int h = chunk / 3, type = chunk % 3;
        size_t base = ((size_t)(bb * NH + h) * 3 + type) * (64 * 1024);
        bool mine = (mw0 >> 6) == half;

        if (type < 2) {
            float scl = (type == 0) ? QSCALE : 1.0f;
            if (mine)
                for (int mt = 0; mt < 4; ++mt)
                    for (int nt = 0; nt < 4; ++nt)
                        for (int r = 0; r < 4; ++r) {
                            int mw = mt * 16 + quad * 4 + r;          // 0..63 within chunk
                            int tl = nw0 + nt * 16 + l15;             // 0..127
                            float v = (acc[mt][nt][r] + bq[o0 + half * 64 + mw]) * scl;
                            sB[tl * 72 + mw] = (bf16_t)v;
                        }
            __syncthreads();
            for (int i = 0; i < 4; ++i) {
                int v = tid + i * 256;
                int tl = v >> 3, c8 = v & 7;
                bf16x8 d = *reinterpret_cast<const bf16x8*>(sB + tl * 72 + c8 * 8);
                *reinterpret_cast<bf16x8*>(qkv + base + (size_t)(t0 + tl) * 64 + c8 * 8) = d;
            }
            __syncthreads();
        } else {
            if (mine)
                for (int mt = 0; mt < 4; ++mt)
                    for (int nt = 0; nt < 4; ++nt)
                        for (int r = 0; r < 4; ++r) {
                            int mw = mt * 16 + quad * 4 + r;
                            int tl = nw0 + nt * 16 + l15;
                            float v = acc[mt][nt][r] + bq[o0 + half * 64 + mw];
                            sB[mw * 136 + tl] = (bf16_t)v;
                        }
            __syncthreads();
            for (int i = 0; i < 4; ++i) {
                int v = tid + i * 256;
                int cc = v >> 4, t8 = (v & 15) * 8;
                bf16x8 d = *reinterpret_cast<const bf16x8*>(sB + cc * 136 + t8);
                *reinterpret_cast<bf16x8*>(qkv + base + (size_t)cc * 1024 + t0 + t8) = d;
            }
            __syncthreads();
        }
    }
}

// ---------------------------------------------------------------------------
// Kernel 3: flash attention, round 14: quad-buffered LDS (72 KB), ONE
// lgkmcnt-barrier per TWO tiles (8 epochs instead of 16).  Each epoch:
// write 2 staged tiles -> issue 8 global loads -> compute 2 tiles -> barrier.
// compute_tile body identical to the verified R2/R4 version.
// ---------------------------------------------------------------------------
__global__ __launch_bounds__(256, 2) void attn_kernel(const bf16_t* __restrict__ qkv,
                                                      bf16_t* __restrict__ net_t)
{
    __shared__ bf16_t sK[4][64 * 72];
    __shared__ bf16_t sV[4][64 * 72];
    int tid = threadIdx.x;
    int w = tid >> 6, lane = tid & 63, quad = lane >> 4, l15 = lane & 15;
    int bh = blockIdx.x;
    int qt = blockIdx.y;                 // 0..7, 128 t-rows per block
    size_t qb = (size_t)bh * 3 * 65536;
    const bf16_t* Qg = qkv + qb + (size_t)qt * 8192;   // 128 rows x 64
    const bf16_t* Kg = qkv + qb + 65536;
    const bf16_t* Vg = qkv + qb + 2 * 65536;

    bf16x8 qf[2][2];
    for (int tt = 0; tt < 2; ++tt)
        for (int kk = 0; kk < 2; ++kk)
            qf[tt][kk] = *reinterpret_cast<const bf16x8*>(
                Qg + (size_t)(tt * 64 + w * 16 + l15) * 64 + kk * 32 + quad * 8);

    int vrow = tid >> 3;            // 0..31
    int vcol = (tid & 7) * 8;       // 0..56

    bf16x8 kA[2], vA[2], kB[2], vB[2];

    auto load_tiles = [&](bf16x8* kr, bf16x8* vr, int s0) {
        for (int i = 0; i < 2; ++i) {
            int r = vrow + i * 32;
            kr[i] = *reinterpret_cast<const bf16x8*>(Kg + (size_t)(s0 + r) * 64 + vcol);
            vr[i] = *reinterpret_cast<const bf16x8*>(Vg + (size_t)r * 1024 + s0 + vcol);
        }
    };
    auto write_tiles = [&](bf16_t* sKb, bf16_t* sVb, const bf16x8* kr, const bf16x8* vr) {
        for (int i = 0; i < 2; ++i) {
            int r = vrow + i * 32;
            *reinterpret_cast<bf16x8*>(sKb + r * 72 + vcol) = kr[i];
            *reinterpret_cast<bf16x8*>(sVb + r * 72 + vcol) = vr[i];
        }
    };

    f32x4 O0[4], O1[4];
    for (int i = 0; i < 4; ++i) {
        O0[i] = f32x4{0.f, 0.f, 0.f, 0.f};
        O1[i] = f32x4{0.f, 0.f, 0.f, 0.f};
    }
    f32x4 L0 = f32x4{0.f, 0.f, 0.f, 0.f};
    f32x4 L1 = f32x4{0.f, 0.f, 0.f, 0.f};
    const bf16x4 kONES = bf16x4{(bf16_t)1.f, (bf16_t)1.f, (bf16_t)1.f, (bf16_t)1.f};

    auto compute_tile = [&](const bf16_t* sKb, const bf16_t* sVb) {
        __builtin_amdgcn_s_setprio(1);
        for (int mt = 0; mt < 4; ++mt) {
            const bf16_t* krow = sKb + (mt * 16 + l15) * 72 + quad * 8;
            bf16x8 kf0 = *reinterpret_cast<const bf16x8*>(krow);
            bf16x8 kf1 = *reinterpret_cast<const bf16x8*>(krow + 32);
            f32x4 S0 = f32x4{0.f, 0.f, 0.f, 0.f};
            f32x4 S1 = f32x4{0.f, 0.f, 0.f, 0.f};
            S0 = __builtin_amdgcn_mfma_f32_16x16x32_bf16(kf0, qf[0][0], S0, 0, 0, 0);
            S1 = __builtin_amdgcn_mfma_f32_16x16x32_bf16(kf0, qf[1][0], S1, 0, 0, 0);
            S0 = __builtin_amdgcn_mfma_f32_16x16x32_bf16(kf1, qf[0][1], S0, 0, 0, 0);
            S1 = __builtin_amdgcn_mfma_f32_16x16x32_bf16(kf1, qf[1][1], S1, 0, 0, 0);
            bf16x4 pf0, pf1;
            for (int r = 0; r < 4; ++r) {
                pf0[r] = (bf16_t)__builtin_amdgcn_exp2f(S0[r]);
                pf1[r] = (bf16_t)__builtin_amdgcn_exp2f(S1[r]);
            }
            L0 = mfma16_bf16(kONES, pf0, L0);
            L1 = mfma16_bf16(kONES, pf1, L1);
            for (int ct = 0; ct < 4; ++ct) {
                bf16x4 vf = *reinterpret_cast<const bf16x4*>(sVb + (ct * 16 + l15) * 72 + mt * 16 + quad * 4);
                O0[ct] = mfma16_bf16(vf, pf0, O0[ct]);
                O1[ct] = mfma16_bf16(vf, pf1, O1[ct]);
            }
        }
        __builtin_amdgcn_s_setprio(0);
    };

    // prologue: tiles 0,1 -> bufs 0,1; tiles 2,3 -> regs
    load_tiles(kA, vA, 0);
    load_tiles(kB, vB, 64);
    write_tiles(sK[0], sV[0], kA, vA);
    write_tiles(sK[1], sV[1], kB, vB);
    load_tiles(kA, vA, 128);
    load_tiles(kB, vB, 192);
    block_sync_lds();

    for (int ep = 0; ep < 4; ++ep) {
        // even epoch e=2ep: tiles {4ep, 4ep+1} from bufs {0,1};
        // stage tiles {4ep+2, 4ep+3} (in regs) -> bufs {2,3};
        // load tiles {4ep+4, 4ep+5} -> regs.
        write_tiles(sK[2], sV[2], kA, vA);
        write_tiles(sK[3], sV[3], kB, vB);
        if (ep < 3) {
            load_tiles(kA, vA, (4 * ep + 4) * 64);
            load_tiles(kB, vB, (4 * ep + 5) * 64);
        }
        compute_tile(sK[0], sV[0]);
        compute_tile(sK[1], sV[1]);
        block_sync_lds();
        // odd epoch e=2ep+1: tiles {4ep+2, 4ep+3} from bufs {2,3};
        // stage tiles {4ep+4, 4ep+5} -> bufs {0,1};
        // load tiles {4ep+6, 4ep+7} -> regs.
        if (ep < 3) {
            write_tiles(sK[0], sV[0], kA, vA);
            write_tiles(sK[1], sV[1], kB, vB);
            load_tiles(kA, vA, (4 * ep + 6) * 64);
            load_tiles(kB, vB, (4 * ep + 7) * 64);
        }
        compute_tile(sK[2], sV[2]);
        compute_tile(sK[3], sV[3]);
        if (ep < 3) block_sync_lds();
    }

    float inv0 = 1.f / L0[0];
    float inv1 = 1.f / L1[0];

    int bb = bh >> 3, h = bh & 7;
    int tbase = qt * 128 + w * 16 + l15;
    bf16_t* orow0 = net_t + ((size_t)bb * T_DIM + tbase) * C_DIM + h * 64;
    bf16_t* orow1 = net_t + ((size_t)bb * T_DIM + tbase + 64) * C_DIM + h * 64;
    for (int ct = 0; ct < 4; ++ct) {
        bf16x4 o4, o5;
        for (int r = 0; r < 4; ++r) {
            o4[r] = (bf16_t)(O0[ct][r] * inv0);
            o5[r] = (bf16_t)(O1[ct][r] * inv1);
        }
        *reinterpret_cast<bf16x4*>(orow0 + ct * 16 + quad * 4) = o4;
        *reinterpret_cast<bf16x4*>(orow1 + ct * 16 + quad * 4) = o5;
    }
}

// ---------------------------------------------------------------------------
// Kernel 4: out GEMM + bias + residual (unchanged).
// ---------------------------------------------------------------------------
__global__ __launch_bounds__(256) void out_gemm_kernel(
    const bf16_t* __restrict__ wob, const float* __restrict__ bo,
    const bf16_t* __restrict__ net_t, const float* __restrict__ x,
    float* __restrict__ out)
{
    __shared__ bf16_t sA[64 * 72];
    __shared__ bf16_t sB[128 * 72];
    int tid = threadIdx.x;
    int w = tid >> 6, lane = tid & 63, quad = lane >> 4, l15 = lane & 15;
    int o0 = blockIdx.x * 64;
    int t0 = blockIdx.y * 128;
    int bb = blockIdx.z;
    const bf16_t* Ab = wob + (size_t)o0 * C_DIM;
    const bf16_t* Bb = net_t + ((size_t)bb * T_DIM + t0) * C_DIM;

    f32x4 acc[2][4];
    for (int mt = 0; mt < 2; ++mt)
        for (int nt = 0; nt < 4; ++nt)
            acc[mt][nt] = f32x4{0.f, 0.f, 0.f, 0.f};
    int mw0 = (w >> 1) * 32;
    int nw0 = (w & 1) * 64;

    for (int k0 = 0; k0 < C_DIM; k0 += 64) {
        for (int i = 0; i < 2; ++i) {
            int v = tid + i * 256;
            int row = v >> 3, c8 = v & 7;
            *reinterpret_cast<bf16x8*>(sA + row * 72 + c8 * 8) =
                *reinterpret_cast<const bf16x8*>(Ab + (size_t)row * C_DIM + k0 + c8 * 8);
        }
        for (int i = 0; i < 4; ++i) {
            int v = tid + i * 256;
            int row = v >> 3, c8 = v & 7;
            *reinterpret_cast<bf16x8*>(sB + row * 72 + c8 * 8) =
                *reinterpret_cast<const bf16x8*>(Bb + (size_t)row * C_DIM + k0 + c8 * 8);
        }
        __syncthreads();
        for (int kk = 0; kk < 2; ++kk) {
            bf16x8 af[2], bfr[4];
            for (int mt = 0; mt < 2; ++mt)
                af[mt] = *reinterpret_cast<const bf16x8*>(sA + (mw0 + mt * 16 + l15) * 72 + kk * 32 + quad * 8);
            for (int nt = 0; nt < 4; ++nt)
                bfr[nt] = *reinterpret_cast<const bf16x8*>(sB + (nw0 + nt * 16 + l15) * 72 + kk * 32 + quad * 8);
            for (int mt = 0; mt < 2; ++mt)
                for (int nt = 0; nt < 4; ++nt)
                    acc[mt][nt] = __builtin_amdgcn_mfma_f32_16x16x32_bf16(af[mt], bfr[nt], acc[mt][nt], 0, 0, 0);
        }
        __syncthreads();
    }

    for (int mt = 0; mt < 2; ++mt)
        for (int nt = 0; nt < 4; ++nt)
            for (int r = 0; r < 4; ++r) {
                int o = o0 + mw0 + mt * 16 + quad * 4 + r;
                int t = t0 + nw0 + nt * 16 + l15;
                size_t idx = ((size_t)bb * C_DIM + o) * T_DIM + t;
                out[idx] = acc[mt][nt][r] + bo[o] + x[idx];
            }
}

// ---------------------------------------------------------------------------
extern "C" void kernel_launch(void* const* d_in, const int* in_sizes, int n_in,
                              void* d_out, int out_size, void* d_ws, size_t ws_size,
                              hipStream_t stream)
{
    const float* x     = (const float*)d_in[0];
    const float* gn_w  = (const float*)d_in[1];
    const float* gn_b  = (const float*)d_in[2];
    const float* qkv_w = (const float*)d_in[3];
    const float* qkv_b = (const float*)d_in[4];
    const float* out_w = (const float*)d_in[5];
    const float* out_b = (const float*)d_in[6];
    float* out = (float*)d_out;

    // ws layout (bf16): n_t 8MB | qkv 24MB | net_t 8MB | wqb 1.5MB | wob 0.5MB
    char* ws = (char*)d_ws;
    bf16_t* n_t   = (bf16_t*)(ws);
    bf16_t* qkv   = (bf16_t*)(ws + 8388608);
    bf16_t* net_t = (bf16_t*)(ws + 33554432);
    bf16_t* wqb   = (bf16_t*)(ws + 41943040);
    bf16_t* wob   = (bf16_t*)(ws + 41943040 + 1572864);

    gn_kernel<<<dim3(320), 256, 0, stream>>>(x, gn_w, gn_b, n_t, qkv_w, out_w, wqb, wob);
    qkv_gemm_kernel<<<dim3(12, 8, 8), 256, 0, stream>>>(wqb, qkv_b, n_t, qkv);
    attn_kernel<<<dim3(64, 8), 256, 0, stream>>>(qkv, net_t);
    out_gemm_kernel<<<dim3(8, 8, 8), 256, 0, stream>>>(wob, out_b, net_t, x, out);
}

// Round 6
// 145.183 us; speedup vs baseline: 1.0533x; 1.0311x over previous
//
#include <hip/hip_runtime.h>
#include <hip/hip_bf16.h>

typedef __bf16 bf16_t;
typedef __bf16 bf16x8 __attribute__((ext_vector_type(8)));
typedef __bf16 bf16x4 __attribute__((ext_vector_type(4)));
typedef short  s16x4  __attribute__((ext_vector_type(4)));
typedef float  f32x4  __attribute__((ext_vector_type(4)));

#define B_DIM 8
#define C_DIM 512
#define T_DIM 1024
#define NH 8
#define HD 64

// softmax scale^2 * log2(e), folded into Q at the qkv epilogue
#define QSCALE 0.180336880111112f

#define GAS __attribute__((address_space(1)))
#define LAS __attribute__((address_space(3)))

// v_mfma_f32_16x16x16_bf16 (gfx950 ISA §10): A/B = 4 bf16 (2 VGPRs),
// operand layout k=quad*4+j, m/n=l15; C row=quad*4+r, col=l15.
__device__ __forceinline__ f32x4 mfma16_bf16(bf16x4 a, bf16x4 b, f32x4 c) {
    return __builtin_amdgcn_mfma_f32_16x16x16bf16_1k(
        __builtin_bit_cast(s16x4, a), __builtin_bit_cast(s16x4, b), c, 0, 0, 0);
}

// raw barrier: make LDS writes visible, but do NOT drain vmcnt (prefetch
// loads stay in flight across the barrier — T4 style).
__device__ __forceinline__ void block_sync_lds() {
    asm volatile("s_waitcnt lgkmcnt(0)" ::: "memory");
    __builtin_amdgcn_s_barrier();
}

// m97-style barrier for global_load_lds staging: drain vmcnt, barrier, and a
// compiler memory fence so LDS reads can't hoist above the barrier.
__device__ __forceinline__ void stage_sync() {
    asm volatile("s_waitcnt vmcnt(0)" ::: "memory");
    __builtin_amdgcn_s_barrier();
    asm volatile("" ::: "memory");
}

// direct global->LDS, 16B per lane.  LDS dest = (uniform base) + lane*16.
__device__ __forceinline__ void gload_lds16(const bf16_t* g, bf16_t* l) {
    __builtin_amdgcn_global_load_lds((const GAS void*)g, (LAS void*)l, 16, 0, 0);
}

// ---------------------------------------------------------------------------
// Kernel 1: GroupNorm + fused one-time weight conversion (unchanged R5).
// ---------------------------------------------------------------------------
__global__ __launch_bounds__(256) void gn_kernel(const float* __restrict__ x,
                                                 const float* __restrict__ gw,
                                                 const float* __restrict__ gb,
                                                 bf16_t* __restrict__ n_t,
                                                 const float* __restrict__ w1,
                                                 const float* __restrict__ w2,
                                                 bf16_t* __restrict__ o1,
                                                 bf16_t* __restrict__ o2)
{
    __shared__ bf16_t sX[16384];
    __shared__ float sred[8];
    int tid = threadIdx.x;

    if (blockIdx.x >= 256) {
        int tid2 = (blockIdx.x - 256) * 256 + tid;
        for (int p = 0; p < 16; ++p) {
            int q = tid2 + p * 16384;
            const f32x4* src;
            bf16x4* dst;
            int qq;
            if (q < 196608) { src = (const f32x4*)w1; dst = (bf16x4*)o1; qq = q; }
            else            { src = (const f32x4*)w2; dst = (bf16x4*)o2; qq = q - 196608; }
            f32x4 f = src[qq];
            bf16x4 h;
            for (int j = 0; j < 4; ++j) h[j] = (bf16_t)f[j];
            dst[qq] = h;
        }
        return;
    }

    int bb  = blockIdx.x >> 5;
    int g   = blockIdx.x & 31;
    const f32x4* xg4 = reinterpret_cast<const f32x4*>(x + (size_t)(bb * C_DIM + g * 16) * T_DIM);

    float s = 0.f, sq = 0.f;
    for (int i = 0; i < 16; ++i) {
        int v = tid + i * 256;
        f32x4 f = xg4[v];
        bf16x4 h;
        for (int j = 0; j < 4; ++j) {
            s += f[j]; sq += f[j] * f[j];
            h[j] = (bf16_t)f[j];
        }
        *reinterpret_cast<bf16x4*>(sX + v * 4) = h;
    }
    for (int off = 1; off < 64; off <<= 1) {
        s  += __shfl_xor(s, off);
        sq += __shfl_xor(sq, off);
    }
    int wv = tid >> 6;
    if ((tid & 63) == 0) { sred[wv * 2] = s; sred[wv * 2 + 1] = sq; }
    __syncthreads();
    s  = sred[0] + sred[2] + sred[4] + sred[6];
    sq = sred[1] + sred[3] + sred[5] + sred[7];
    float mean = s * (1.f / 16384.f);
    float var  = sq * (1.f / 16384.f) - mean * mean;
    float rs   = rsqrtf(var + 1e-5f);

    int hf = tid & 1;
    float aa[8], bbias[8];
    for (int j = 0; j < 8; ++j) {
        int c = hf * 8 + j;
        float av = gw[g * 16 + c] * rs;
        aa[j] = av;
        bbias[j] = gb[g * 16 + c] - mean * av;
    }
    bf16_t* ob = n_t + (size_t)bb * T_DIM * C_DIM + g * 16 + hf * 8;
    for (int p = 0; p < 8; ++p) {
        int t = (tid >> 1) + p * 128;
        bf16x8 o;
        for (int j = 0; j < 8; ++j) {
            float xv = (float)sX[(hf * 8 + j) * 1024 + t];
            o[j] = (bf16_t)(xv * aa[j] + bbias[j]);
        }
        *reinterpret_cast<bf16x8*>(ob + (size_t)t * C_DIM) = o;
    }
}

// ---------------------------------------------------------------------------
// Kernel 2: QKV GEMM, round 15: global_load_lds staging (m97 structure).
// LDS tiles are UNPADDED [rows][64] with XOR swizzle: physical 16B-slot p of
// row r holds logical slot p^(r&7); achieved by pre-swizzling the per-lane
// GLOBAL source (rule #21: both-sides-or-neither).  Fragment ds_reads apply
// the same XOR.  MFMA math / accumulators / epilogue identical to R4.
// ---------------------------------------------------------------------------
__global__ __launch_bounds__(256, 4) void qkv_gemm_kernel(
    const bf16_t* __restrict__ wqb, const float* __restrict__ bq,
    const bf16_t* __restrict__ n_t, bf16_t* __restrict__ qkv)
{
    __shared__ __align__(16) bf16_t smem[16384];   // 32 KB: sA | sB
    bf16_t* sA = smem;            // 128 rows x 64 (16 KB)
    bf16_t* sB = smem + 8192;     // 128 rows x 64 (16 KB)
    int tid = threadIdx.x;
    int w = tid >> 6, lane = tid & 63, quad = lane >> 4, l15 = lane & 15;
    int bx = blockIdx.x;          // 0..11  (two 64-row chunks each)
    int t0 = blockIdx.y * 128;
    int bb = blockIdx.z;
    int o0 = bx * 128;
    const bf16_t* Ab = wqb + (size_t)o0 * C_DIM;
    const bf16_t* Bb = n_t + ((size_t)bb * T_DIM + t0) * C_DIM;

    f32x4 acc[4][4];
    for (int mt = 0; mt < 4; ++mt)
        for (int nt = 0; nt < 4; ++nt)
            acc[mt][nt] = f32x4{0.f, 0.f, 0.f, 0.f};
    int mw0 = (w >> 1) * 64;      // 0 or 64
    int nw0 = (w & 1) * 64;       // 0 or 64

    // per-lane source row/col for staging (row&7 == lane>>3 for all issues)
    int srow = (lane >> 3);             // + i*32 + w*8
    int scol = ((lane & 7) ^ srow) * 8; // pre-swizzled logical col (elems)

    for (int k0 = 0; k0 < C_DIM; k0 += 64) {
        for (int i = 0; i < 4; ++i) {
            int row = i * 32 + w * 8 + srow;
            gload_lds16(Ab + (size_t)row * C_DIM + k0 + scol, sA + i * 2048 + w * 512);
        }
        for (int i = 0; i < 4; ++i) {
            int row = i * 32 + w * 8 + srow;
            gload_lds16(Bb + (size_t)row * C_DIM + k0 + scol, sB + i * 2048 + w * 512);
        }
        stage_sync();
        for (int kk = 0; kk < 2; ++kk) {
            bf16x8 af[4], bfr[4];
            for (int mt = 0; mt < 4; ++mt) {
                int row = mw0 + mt * 16 + l15;
                int cs = kk * 4 + quad;                       // logical 16B slot
                af[mt] = *reinterpret_cast<const bf16x8*>(sA + row * 64 + ((cs ^ (row & 7)) << 3));
            }
            for (int nt = 0; nt < 4; ++nt) {
                int row = nw0 + nt * 16 + l15;
                int cs = kk * 4 + quad;
                bfr[nt] = *reinterpret_cast<const bf16x8*>(sB + row * 64 + ((cs ^ (row & 7)) << 3));
            }
            for (int mt = 0; mt < 4; ++mt)
                for (int nt = 0; nt < 4; ++nt)
                    acc[mt][nt] = __builtin_amdgcn_mfma_f32_16x16x32_bf16(af[mt], bfr[nt], acc[mt][nt], 0, 0, 0);
        }
        __builtin_amdgcn_s_barrier();
    }

    // epilogue: two 64-row output chunks; wave-half (w>>1) owns chunk half.
    // scratch reuses the whole 32 KB smem (padded layouts as in R4).
    bf16_t* es = smem;
    for (int half = 0; half < 2; ++half) {
        int chunk = bx * 2 + half;
        int h = chunk / 3, type = chunk % 3;
        size_t base = ((size_t)(bb * NH + h) * 3 + type) * (64 * 1024);
        bool mine = (mw0 >> 6) == half;

        if (type < 2) {
            float scl = (type == 0) ? QSCALE : 1.0f;
            if (mine)
                for (int mt = 0; mt < 4; ++mt)
                    for (int nt = 0; nt < 4; ++nt)
                        for (int r = 0; r < 4; ++r) {
                            int mw = mt * 16 + quad * 4 + r;          // 0..63 within chunk
                            int tl = nw0 + nt * 16 + l15;             // 0..127
                            float v = (acc[mt][nt][r] + bq[o0 + half * 64 + mw]) * scl;
                            es[tl * 72 + mw] = (bf16_t)v;
                        }
            __syncthreads();
            for (int i = 0; i < 4; ++i) {
                int v = tid + i * 256;
                int tl = v >> 3, c8 = v & 7;
                bf16x8 d = *reinterpret_cast<const bf16x8*>(es + tl * 72 + c8 * 8);
                *reinterpret_cast<bf16x8*>(qkv + base + (size_t)(t0 + tl) * 64 + c8 * 8) = d;
            }
            __syncthreads();
        } else {
            if (mine)
                for (int mt = 0; mt < 4; ++mt)
                    for (int nt = 0; nt < 4; ++nt)
                        for (int r = 0; r < 4; ++r) {
                            int mw = mt * 16 + quad * 4 + r;
                            int tl = nw0 + nt * 16 + l15;
                            float v = acc[mt][nt][r] + bq[o0 + half * 64 + mw];
                            es[mw * 136 + tl] = (bf16_t)v;
                        }
            __syncthreads();
            for (int i = 0; i < 4; ++i) {
                int v = tid + i * 256;
                int cc = v >> 4, t8 = (v & 15) * 8;
                bf16x8 d = *reinterpret_cast<const bf16x8*>(es + cc * 136 + t8);
                *reinterpret_cast<bf16x8*>(qkv + base + (size_t)cc * 1024 + t0 + t8) = d;
            }
            __syncthreads();
        }
    }
}

// ---------------------------------------------------------------------------
// Kernel 3: flash attention (unchanged from R5: quad-buffered, 8 epochs).
// ---------------------------------------------------------------------------
__global__ __launch_bounds__(256, 2) void attn_kernel(const bf16_t* __restrict__ qkv,
                                                      bf16_t* __restrict__ net_t)
{
    __shared__ bf16_t sK[4][64 * 72];
    __shared__ bf16_t sV[4][64 * 72];
    int tid = threadIdx.x;
    int w = tid >> 6, lane = tid & 63, quad = lane >> 4, l15 = lane & 15;
    int bh = blockIdx.x;
    int qt = blockIdx.y;                 // 0..7, 128 t-rows per block
    size_t qb = (size_t)bh * 3 * 65536;
    const bf16_t* Qg = qkv + qb + (size_t)qt * 8192;   // 128 rows x 64
    const bf16_t* Kg = qkv + qb + 65536;
    const bf16_t* Vg = qkv + qb + 2 * 65536;

    bf16x8 qf[2][2];
    for (int tt = 0; tt < 2; ++tt)
        for (int kk = 0; kk < 2; ++kk)
            qf[tt][kk] = *reinterpret_cast<const bf16x8*>(
                Qg + (size_t)(tt * 64 + w * 16 + l15) * 64 + kk * 32 + quad * 8);

    int vrow = tid >> 3;            // 0..31
    int vcol = (tid & 7) * 8;       // 0..56

    bf16x8 kA[2], vA[2], kB[2], vB[2];

    auto load_tiles = [&](bf16x8* kr, bf16x8* vr, int s0) {
        for (int i = 0; i < 2; ++i) {
            int r = vrow + i * 32;
            kr[i] = *reinterpret_cast<const bf16x8*>(Kg + (size_t)(s0 + r) * 64 + vcol);
            vr[i] = *reinterpret_cast<const bf16x8*>(Vg + (size_t)r * 1024 + s0 + vcol);
        }
    };
    auto write_tiles = [&](bf16_t* sKb, bf16_t* sVb, const bf16x8* kr, const bf16x8* vr) {
        for (int i = 0; i < 2; ++i) {
            int r = vrow + i * 32;
            *reinterpret_cast<bf16x8*>(sKb + r * 72 + vcol) = kr[i];
            *reinterpret_cast<bf16x8*>(sVb + r * 72 + vcol) = vr[i];
        }
    };

    f32x4 O0[4], O1[4];
    for (int i = 0; i < 4; ++i) {
        O0[i] = f32x4{0.f, 0.f, 0.f, 0.f};
        O1[i] = f32x4{0.f, 0.f, 0.f, 0.f};
    }
    f32x4 L0 = f32x4{0.f, 0.f, 0.f, 0.f};
    f32x4 L1 = f32x4{0.f, 0.f, 0.f, 0.f};
    const bf16x4 kONES = bf16x4{(bf16_t)1.f, (bf16_t)1.f, (bf16_t)1.f, (bf16_t)1.f};

    auto compute_tile = [&](const bf16_t* sKb, const bf16_t* sVb) {
        __builtin_amdgcn_s_setprio(1);
        for (int mt = 0; mt < 4; ++mt) {
            const bf16_t* krow = sKb + (mt * 16 + l15) * 72 + quad * 8;
            bf16x8 kf0 = *reinterpret_cast<const bf16x8*>(krow);
            bf16x8 kf1 = *reinterpret_cast<const bf16x8*>(krow + 32);
            f32x4 S0 = f32x4{0.f, 0.f, 0.f, 0.f};
            f32x4 S1 = f32x4{0.f, 0.f, 0.f, 0.f};
            S0 = __builtin_amdgcn_mfma_f32_16x16x32_bf16(kf0, qf[0][0], S0, 0, 0, 0);
            S1 = __builtin_amdgcn_mfma_f32_16x16x32_bf16(kf0, qf[1][0], S1, 0, 0, 0);
            S0 = __builtin_amdgcn_mfma_f32_16x16x32_bf16(kf1, qf[0][1], S0, 0, 0, 0);
            S1 = __builtin_amdgcn_mfma_f32_16x16x32_bf16(kf1, qf[1][1], S1, 0, 0, 0);
            bf16x4 pf0, pf1;
            for (int r = 0; r < 4; ++r) {
                pf0[r] = (bf16_t)__builtin_amdgcn_exp2f(S0[r]);
                pf1[r] = (bf16_t)__builtin_amdgcn_exp2f(S1[r]);
            }
            L0 = mfma16_bf16(kONES, pf0, L0);
            L1 = mfma16_bf16(kONES, pf1, L1);
            for (int ct = 0; ct < 4; ++ct) {
                bf16x4 vf = *reinterpret_cast<const bf16x4*>(sVb + (ct * 16 + l15) * 72 + mt * 16 + quad * 4);
                O0[ct] = mfma16_bf16(vf, pf0, O0[ct]);
                O1[ct] = mfma16_bf16(vf, pf1, O1[ct]);
            }
        }
        __builtin_amdgcn_s_setprio(0);
    };

    // prologue: tiles 0,1 -> bufs 0,1; tiles 2,3 -> regs
    load_tiles(kA, vA, 0);
    load_tiles(kB, vB, 64);
    write_tiles(sK[0], sV[0], kA, vA);
    write_tiles(sK[1], sV[1], kB, vB);
    load_tiles(kA, vA, 128);
    load_tiles(kB, vB, 192);
    block_sync_lds();

    for (int ep = 0; ep < 4; ++ep) {
        write_tiles(sK[2], sV[2], kA, vA);
        write_tiles(sK[3], sV[3], kB, vB);
        if (ep < 3) {
            load_tiles(kA, vA, (4 * ep + 4) * 64);
            load_tiles(kB, vB, (4 * ep + 5) * 64);
        }
        compute_tile(sK[0], sV[0]);
        compute_tile(sK[1], sV[1]);
        block_sync_lds();
        if (ep < 3) {
            write_tiles(sK[0], sV[0], kA, vA);
            write_tiles(sK[1], sV[1], kB, vB);
            load_tiles(kA, vA, (4 * ep + 6) * 64);
            load_tiles(kB, vB, (4 * ep + 7) * 64);
        }
        compute_tile(sK[2], sV[2]);
        compute_tile(sK[3], sV[3]);
        if (ep < 3) block_sync_lds();
    }

    float inv0 = 1.f / L0[0];
    float inv1 = 1.f / L1[0];

    int bb = bh >> 3, h = bh & 7;
    int tbase = qt * 128 + w * 16 + l15;
    bf16_t* orow0 = net_t + ((size_t)bb * T_DIM + tbase) * C_DIM + h * 64;
    bf16_t* orow1 = net_t + ((size_t)bb * T_DIM + tbase + 64) * C_DIM + h * 64;
    for (int ct = 0; ct < 4; ++ct) {
        bf16x4 o4, o5;
        for (int r = 0; r < 4; ++r) {
            o4[r] = (bf16_t)(O0[ct][r] * inv0);
            o5[r] = (bf16_t)(O1[ct][r] * inv1);
        }
        *reinterpret_cast<bf16x4*>(orow0 + ct * 16 + quad * 4) = o4;
        *reinterpret_cast<bf16x4*>(orow1 + ct * 16 + quad * 4) = o5;
    }
}

// ---------------------------------------------------------------------------
// Kernel 4: out GEMM + bias + residual, round 15: global_load_lds staging
// with the same XOR-swizzled unpadded LDS tiles.  MFMA/epilogue unchanged.
// ---------------------------------------------------------------------------
__global__ __launch_bounds__(256) void out_gemm_kernel(
    const bf16_t* __restrict__ wob, const float* __restrict__ bo,
    const bf16_t* __restrict__ net_t, const float* __restrict__ x,
    float* __restrict__ out)
{
    __shared__ __align__(16) bf16_t smem[12288];   // 24 KB: sA(64x64) | sB(128x64)
    bf16_t* sA = smem;            // 64 rows x 64 (8 KB)
    bf16_t* sB = smem + 4096;     // 128 rows x 64 (16 KB)
    int tid = threadIdx.x;
    int w = tid >> 6, lane = tid & 63, quad = lane >> 4, l15 = lane & 15;
    int o0 = blockIdx.x * 64;
    int t0 = blockIdx.y * 128;
    int bb = blockIdx.z;
    const bf16_t* Ab = wob + (size_t)o0 * C_DIM;
    const bf16_t* Bb = net_t + ((size_t)bb * T_DIM + t0) * C_DIM;

    f32x4 acc[2][4];
    for (int mt = 0; mt < 2; ++mt)
        for (int nt = 0; nt < 4; ++nt)
            acc[mt][nt] = f32x4{0.f, 0.f, 0.f, 0.f};
    int mw0 = (w >> 1) * 32;
    int nw0 = (w & 1) * 64;

    int srow = (lane >> 3);
    int scol = ((lane & 7) ^ srow) * 8;

    for (int k0 = 0; k0 < C_DIM; k0 += 64) {
        for (int i = 0; i < 2; ++i) {
            int row = i * 32 + w * 8 + srow;
            gload_lds16(Ab + (size_t)row * C_DIM + k0 + scol, sA + i * 2048 + w * 512);
        }
        for (int i = 0; i < 4; ++i) {
            int row = i * 32 + w * 8 + srow;
            gload_lds16(Bb + (size_t)row * C_DIM + k0 + scol, sB + i * 2048 + w * 512);
        }
        stage_sync();
        for (int kk = 0; kk < 2; ++kk) {
            bf16x8 af[2], bfr[4];
            for (int mt = 0; mt < 2; ++mt) {
                int row = mw0 + mt * 16 + l15;
                int cs = kk * 4 + quad;
                af[mt] = *reinterpret_cast<const bf16x8*>(sA + row * 64 + ((cs ^ (row & 7)) << 3));
            }
            for (int nt = 0; nt < 4; ++nt) {
                int row = nw0 + nt * 16 + l15;
                int cs = kk * 4 + quad;
                bfr[nt] = *reinterpret_cast<const bf16x8*>(sB + row * 64 + ((cs ^ (row & 7)) << 3));
            }
            for (int mt = 0; mt < 2; ++mt)
                for (int nt = 0; nt < 4; ++nt)
                    acc[mt][nt] = __builtin_amdgcn_mfma_f32_16x16x32_bf16(af[mt], bfr[nt], acc[mt][nt], 0, 0, 0);
        }
        __builtin_amdgcn_s_barrier();
    }

    for (int mt = 0; mt < 2; ++mt)
        for (int nt = 0; nt < 4; ++nt)
            for (int r = 0; r < 4; ++r) {
                int o = o0 + mw0 + mt * 16 + quad * 4 + r;
                int t = t0 + nw0 + nt * 16 + l15;
                size_t idx = ((size_t)bb * C_DIM + o) * T_DIM + t;
                out[idx] = acc[mt][nt][r] + bo[o] + x[idx];
            }
}

// ---------------------------------------------------------------------------
extern "C" void kernel_launch(void* const* d_in, const int* in_sizes, int n_in,
                              void* d_out, int out_size, void* d_ws, size_t ws_size,
                              hipStream_t stream)
{
    const float* x     = (const float*)d_in[0];
    const float* gn_w  = (const float*)d_in[1];
    const float* gn_b  = (const float*)d_in[2];
    const float* qkv_w = (const float*)d_in[3];
    const float* qkv_b = (const float*)d_in[4];
    const float* out_w = (const float*)d_in[5];
    const float* out_b = (const float*)d_in[6];
    float* out = (float*)d_out;

    // ws layout (bf16): n_t 8MB | qkv 24MB | net_t 8MB | wqb 1.5MB | wob 0.5MB
    char* ws = (char*)d_ws;
    bf16_t* n_t   = (bf16_t*)(ws);
    bf16_t* qkv   = (bf16_t*)(ws + 8388608);
    bf16_t* net_t = (bf16_t*)(ws + 33554432);
    bf16_t* wqb   = (bf16_t*)(ws + 41943040);
    bf16_t* wob   = (bf16_t*)(ws + 41943040 + 1572864);

    gn_kernel<<<dim3(320), 256, 0, stream>>>(x, gn_w, gn_b, n_t, qkv_w, out_w, wqb, wob);
    qkv_gemm_kernel<<<dim3(12, 8, 8), 256, 0, stream>>>(wqb, qkv_b, n_t, qkv);
    attn_kernel<<<dim3(64, 8), 256, 0, stream>>>(qkv, net_t);
    out_gemm_kernel<<<dim3(8, 8, 8), 256, 0, stream>>>(wob, out_b, net_t, x, out);
}